// Round 3
// baseline (2236.604 us; speedup 1.0000x reference)
//
#include <hip/hip_runtime.h>
#include <hip/hip_bf16.h>
#include <stdint.h>

// GRU sequence decoder, fused. B=32768, H=L=512, VOCAB=10, SEQ=6.
// R3: occupancy 2x (BM=64, LDS 64KB, 2 blocks/CU -> 4 waves/SIMD) + gi register
// prefetch ahead of the MFMA k-loop.
//  - A = weight frag (M = j), B = h frag (N = batch); lane holds D[j-contig].
//  - gi in ws in per-lane fragment order (bf16x4/lane): coalesced 512B/wave.
//  - h lives only in LDS (XOR-swizzled); h_new carried in regs across barrier.
//  - Weights pre-shuffled to fragment order (prep kernel), streamed from L2.
//  - 8 waves = wm2 (batch half, 2 btiles) x wn4 (hidden quarter, 8 jtiles);
//    4 passes of {2 jt x 3 gates x 2 bt} => acc 48 f32, hnew 32 VGPR.

typedef __bf16 bf16_t;
typedef bf16_t bf16x8 __attribute__((ext_vector_type(8)));
typedef bf16_t bf16x4 __attribute__((ext_vector_type(4)));
typedef float  f32x4  __attribute__((ext_vector_type(4)));
typedef float  f32x2  __attribute__((ext_vector_type(2)));

#define THREADS 512
#define BM      64
#define NBLK    512
#define NSTEP   6

// ws layout (bytes)
#define WIH_OFF 0u            // 96 nt * 16 kk * 64 lane * 16B = 1572864
#define WHH_OFF 1572864u
#define WOP_OFF 3145728u      // 16 kk * 64 lane * 16B = 16384
#define GI_OFF  4194304u      // 512 blk * 24576 chunks * 8B = 100663296

static __device__ __forceinline__ float sigm(float v) { return 1.0f / (1.0f + __expf(-v)); }
static __device__ __forceinline__ float tanhf_(float v) {
  v = fminf(fmaxf(v, -12.0f), 12.0f);
  float e = __expf(2.0f * v);
  return 1.0f - 2.0f / (e + 1.0f);
}
static __device__ __forceinline__ f32x4 up4(bf16x4 v) {
  f32x4 o; o[0] = (float)v[0]; o[1] = (float)v[1]; o[2] = (float)v[2]; o[3] = (float)v[3];
  return o;
}
static __device__ __forceinline__ bf16x4 pk4(f32x4 v) {
  bf16x4 o; o[0] = (bf16_t)v[0]; o[1] = (bf16_t)v[1]; o[2] = (bf16_t)v[2]; o[3] = (bf16_t)v[3];
  return o;
}

// Pack weights into MFMA A-frag order:
//   chunk[(nt*16 + kk)*64 + lane] = w[nt*16 + (lane&15)][kk*32 + (lane>>4)*8 .. +8]
__global__ void prep_kernel(const float* __restrict__ wih_f, const float* __restrict__ whh_f,
                            const float* __restrict__ wout_f,
                            bf16x8* __restrict__ wihPk, bf16x8* __restrict__ whhPk,
                            bf16x8* __restrict__ wopPk) {
  int c = blockIdx.x * 256 + threadIdx.x;
  int lane = c & 63, l15 = lane & 15, lk = (lane >> 4) & 3;
  if (c < 196608) {
    int cid = (c < 98304) ? c : c - 98304;
    const float* src = (c < 98304) ? wih_f : whh_f;
    bf16x8* dst = (c < 98304) ? wihPk : whhPk;
    int kk = (cid >> 6) & 15;
    int nt = cid >> 10;
    const float* p = src + (size_t)(nt * 16 + l15) * 512 + kk * 32 + lk * 8;
    bf16x8 o;
    #pragma unroll
    for (int i = 0; i < 8; ++i) o[i] = (bf16_t)p[i];
    dst[cid] = o;
  } else if (c < 197632) {
    int cid = c - 196608;          // vocab tile: 16 kk * 64 lane
    int kk = cid >> 6;
    bf16x8 o;
    if (l15 < 10) {
      const float* p = wout_f + (size_t)l15 * 512 + kk * 32 + lk * 8;
      #pragma unroll
      for (int i = 0; i < 8; ++i) o[i] = (bf16_t)p[i];
    } else {
      #pragma unroll
      for (int i = 0; i < 8; ++i) o[i] = (bf16_t)0.0f;
    }
    wopPk[cid] = o;
  }
}

__global__ __launch_bounds__(THREADS, 4) void gru_kernel(
    const float* __restrict__ x, const float* __restrict__ b_ih,
    const float* __restrict__ b_hh, const float* __restrict__ b_out,
    const bf16x8* __restrict__ wih, const bf16x8* __restrict__ whh,
    const bf16x8* __restrict__ wop,
    bf16x4* __restrict__ gi, float* __restrict__ out) {
  // h tile: 64 rows x 512 bf16, row = 1024B, logical byte L of row r stored at
  // physical L ^ ((r&7)<<4).
  __shared__ __align__(16) char hlds[BM * 1024];

  const int tid   = (int)threadIdx.x;
  const int lane  = tid & 63;
  const int wq    = tid >> 6;      // 0..7
  const int wm    = wq >> 2;       // batch half: btiles {wm*2, wm*2+1} (32 rows)
  const int wn    = wq & 3;        // hidden quarter: jtiles [wn*8, wn*8+8)
  const int l15   = lane & 15;
  const int lk    = lane >> 4;
  const int brow0 = (int)blockIdx.x * BM;
  const int swz   = (l15 & 7) << 4;

  // ---------------- phase 0: x -> bf16 -> hlds (h0 = x) ----------------
  #pragma unroll
  for (int it = 0; it < 16; ++it) {
    int f4  = it * THREADS + tid;
    int row = f4 >> 7, c4 = f4 & 127;
    float4 v = ((const float4*)(x + (size_t)(brow0 + row) * 512))[c4];
    bf16x4 h4 = { (bf16_t)v.x, (bf16_t)v.y, (bf16_t)v.z, (bf16_t)v.w };
    *(bf16x4*)(&hlds[row * 1024 + ((c4 * 8) ^ ((row & 7) << 4))]) = h4;
  }
  __syncthreads();

  const size_t gibase = (size_t)blockIdx.x * 24576;  // bf16x4 chunks per block
  // gi chunk: (((wq*8 + jt)*3 + g)*2 + bt)*64 + lane

  // ---------------- gi phase: gi = x @ w_ih^T + biases ----------------
  for (int ng = 0; ng < 4; ++ng) {
    f32x4 acc[2][3][2];
    #pragma unroll
    for (int jj = 0; jj < 2; ++jj)
      #pragma unroll
      for (int g = 0; g < 3; ++g)
        #pragma unroll
        for (int bt = 0; bt < 2; ++bt) acc[jj][g][bt] = (f32x4){0.f, 0.f, 0.f, 0.f};

    #pragma unroll 4
    for (int kk = 0; kk < 16; ++kk) {
      bf16x8 hf[2];
      #pragma unroll
      for (int bt = 0; bt < 2; ++bt)
        hf[bt] = *(const bf16x8*)(&hlds[((wm * 2 + bt) * 16 + l15) * 1024 +
                                        (((kk * 64) | (lk * 16)) ^ swz)]);
      #pragma unroll
      for (int jj = 0; jj < 2; ++jj)
        #pragma unroll
        for (int g = 0; g < 3; ++g) {
          int nt = g * 32 + wn * 8 + ng * 2 + jj;
          bf16x8 wf = wih[(nt * 16 + kk) * 64 + lane];
          #pragma unroll
          for (int bt = 0; bt < 2; ++bt)
            acc[jj][g][bt] = __builtin_amdgcn_mfma_f32_16x16x32_bf16(wf, hf[bt], acc[jj][g][bt], 0, 0, 0);
        }
    }
    #pragma unroll
    for (int jj = 0; jj < 2; ++jj) {
      int jtl = ng * 2 + jj;
      int j   = (wn * 8 + jtl) * 16 + lk * 4;
      f32x4 b0 = *(const f32x4*)(b_ih + j) + *(const f32x4*)(b_hh + j);
      f32x4 b1 = *(const f32x4*)(b_ih + 512 + j) + *(const f32x4*)(b_hh + 512 + j);
      f32x4 b2 = *(const f32x4*)(b_ih + 1024 + j);   // b_hh_n stays separate (x r)
      #pragma unroll
      for (int bt = 0; bt < 2; ++bt) {
        int cb = ((wq * 8 + jtl) * 3) * 2 + bt;
        gi[gibase + ((size_t)(cb + 0) << 6) + lane] = pk4(acc[jj][0][bt] + b0);
        gi[gibase + ((size_t)(cb + 2) << 6) + lane] = pk4(acc[jj][1][bt] + b1);
        gi[gibase + ((size_t)(cb + 4) << 6) + lane] = pk4(acc[jj][2][bt] + b2);
      }
    }
  }
  // (no barrier: hlds unchanged; gi is same-lane RAW, HW-ordered)

  // ---------------- 6 recurrent steps ----------------
  for (int t = 0; t < NSTEP; ++t) {
    bf16x4 hnew[8][2];   // [jt][bt], held across barrier #1
    for (int ng = 0; ng < 4; ++ng) {
      // prefetch this pass's gi chunks (latency hides under the MFMA k-loop)
      bf16x4 gpre[2][3][2];
      #pragma unroll
      for (int jj = 0; jj < 2; ++jj) {
        int cb = ((wq * 8 + ng * 2 + jj) * 3) * 2;
        #pragma unroll
        for (int g = 0; g < 3; ++g)
          #pragma unroll
          for (int bt = 0; bt < 2; ++bt)
            gpre[jj][g][bt] = gi[gibase + ((size_t)(cb + g * 2 + bt) << 6) + lane];
      }

      f32x4 acc[2][3][2];
      #pragma unroll
      for (int jj = 0; jj < 2; ++jj)
        #pragma unroll
        for (int g = 0; g < 3; ++g)
          #pragma unroll
          for (int bt = 0; bt < 2; ++bt) acc[jj][g][bt] = (f32x4){0.f, 0.f, 0.f, 0.f};

      #pragma unroll 4
      for (int kk = 0; kk < 16; ++kk) {
        bf16x8 hf[2];
        #pragma unroll
        for (int bt = 0; bt < 2; ++bt)
          hf[bt] = *(const bf16x8*)(&hlds[((wm * 2 + bt) * 16 + l15) * 1024 +
                                          (((kk * 64) | (lk * 16)) ^ swz)]);
        #pragma unroll
        for (int jj = 0; jj < 2; ++jj)
          #pragma unroll
          for (int g = 0; g < 3; ++g) {
            int nt = g * 32 + wn * 8 + ng * 2 + jj;
            bf16x8 wf = whh[(nt * 16 + kk) * 64 + lane];
            #pragma unroll
            for (int bt = 0; bt < 2; ++bt)
              acc[jj][g][bt] = __builtin_amdgcn_mfma_f32_16x16x32_bf16(wf, hf[bt], acc[jj][g][bt], 0, 0, 0);
          }
      }
      // GRU cell epilogue (gi already in regs)
      #pragma unroll
      for (int jj = 0; jj < 2; ++jj) {
        int jtl = ng * 2 + jj;
        int j   = (wn * 8 + jtl) * 16 + lk * 4;
        f32x4 bn4 = *(const f32x4*)(b_hh + 1024 + j);
        #pragma unroll
        for (int bt = 0; bt < 2; ++bt) {
          f32x4 gr = up4(gpre[jj][0][bt]);
          f32x4 gz = up4(gpre[jj][1][bt]);
          f32x4 gn = up4(gpre[jj][2][bt]);
          bf16x4 ho = *(const bf16x4*)(&hlds[((wm * 2 + bt) * 16 + l15) * 1024 +
                                             ((((wn * 8 + jtl) * 32) | (lk * 8)) ^ swz)]);
          f32x4 hov = up4(ho);
          f32x4 hv;
          #pragma unroll
          for (int r = 0; r < 4; ++r) {
            float rv = sigm(gr[r] + acc[jj][0][bt][r]);
            float zv = sigm(gz[r] + acc[jj][1][bt][r]);
            float nv = tanhf_(gn[r] + rv * (acc[jj][2][bt][r] + bn4[r]));
            hv[r] = (1.0f - zv) * nv + zv * hov[r];
          }
          hnew[jtl][bt] = pk4(hv);
        }
      }
    }
    __syncthreads();   // all waves done reading h_t
    #pragma unroll
    for (int jt = 0; jt < 8; ++jt)
      #pragma unroll
      for (int bt = 0; bt < 2; ++bt)
        *(bf16x4*)(&hlds[((wm * 2 + bt) * 16 + l15) * 1024 +
                         ((((wn * 8 + jt) * 32) | (lk * 8)) ^ swz)]) = hnew[jt][bt];
    __syncthreads();   // h_{t+1} visible

    // logits_t = h_{t+1} @ w_out^T + b_out ; waves 0..3 each own one btile
    if (wq < 4) {
      f32x4 lacc = (f32x4){0.f, 0.f, 0.f, 0.f};
      #pragma unroll 4
      for (int kk = 0; kk < 16; ++kk) {
        bf16x8 hf = *(const bf16x8*)(&hlds[(wq * 16 + l15) * 1024 +
                                           (((kk * 64) | (lk * 16)) ^ swz)]);
        bf16x8 wf = wop[kk * 64 + lane];
        lacc = __builtin_amdgcn_mfma_f32_16x16x32_bf16(wf, hf, lacc, 0, 0, 0);
      }
      size_t ob = (size_t)(brow0 + wq * 16 + l15) * 60 + t * 10 + lk * 4;
      if (lk < 2) {
        f32x2 a = { lacc[0] + b_out[lk * 4 + 0], lacc[1] + b_out[lk * 4 + 1] };
        f32x2 b = { lacc[2] + b_out[lk * 4 + 2], lacc[3] + b_out[lk * 4 + 3] };
        *(f32x2*)(out + ob) = a;
        *(f32x2*)(out + ob + 2) = b;
      } else if (lk == 2) {
        f32x2 a = { lacc[0] + b_out[8], lacc[1] + b_out[9] };
        *(f32x2*)(out + ob) = a;
      }
    }
  }
}

extern "C" void kernel_launch(void* const* d_in, const int* in_sizes, int n_in,
                              void* d_out, int out_size, void* d_ws, size_t ws_size,
                              hipStream_t stream) {
  const float* x     = (const float*)d_in[0];
  const float* wih_f = (const float*)d_in[1];
  const float* whh_f = (const float*)d_in[2];
  const float* b_ih  = (const float*)d_in[3];
  const float* b_hh  = (const float*)d_in[4];
  const float* wout  = (const float*)d_in[5];
  const float* b_out = (const float*)d_in[6];

  char* ws = (char*)d_ws;
  bf16x8* wihPk = (bf16x8*)(ws + WIH_OFF);
  bf16x8* whhPk = (bf16x8*)(ws + WHH_OFF);
  bf16x8* wopPk = (bf16x8*)(ws + WOP_OFF);
  bf16x4* gi    = (bf16x4*)(ws + GI_OFF);

  prep_kernel<<<772, 256, 0, stream>>>(wih_f, whh_f, wout, wihPk, whhPk, wopPk);
  gru_kernel<<<NBLK, THREADS, 0, stream>>>(x, b_ih, b_hh, b_out,
                                           wihPk, whhPk, wopPk, gi, (float*)d_out);
}

// Round 4
// 1186.083 us; speedup vs baseline: 1.8857x; 1.8857x over previous
//
#include <hip/hip_runtime.h>
#include <hip/hip_bf16.h>
#include <stdint.h>

// GRU sequence decoder, fused. B=32768, H=L=512, VOCAB=10, SEQ=6.
// R4: fix launch_bounds (hipcc 2nd arg = min BLOCKS/CU, measured R3: arg 4 ->
// 64-VGPR cap -> spill catastrophe). Now (512,2) -> 128-VGPR cap, 2 blocks/CU,
// 4 waves/SIMD. Wave partition switched to wn8: each wave owns 4 jtiles x all
// 4 btiles -> weight fragments read ONCE per block-step (A-reuse 4): L2 weight
// traffic 9.2 -> 4.6 GB.
//  - A = weight frag (M = j), B = h frag (N = batch); lane holds D[j-contig].
//  - gi in ws in per-lane fragment order (bf16x4/lane): coalesced, same-lane RAW.
//  - h lives only in LDS (XOR-swizzled byte^=(row&7)<<4); h_new in regs across
//    barrier then ds_write_b64.
//  - Per pass {1 jt x 3 gates x 4 bt}: acc 48 f32; gr/gz prefetched (16 VGPR),
//    gn loaded at epilogue start (hides under sigmoid chain). All frag arrays
//    statically indexed (passes unrolled).

typedef __bf16 bf16_t;
typedef bf16_t bf16x8 __attribute__((ext_vector_type(8)));
typedef bf16_t bf16x4 __attribute__((ext_vector_type(4)));
typedef float  f32x4  __attribute__((ext_vector_type(4)));
typedef float  f32x2  __attribute__((ext_vector_type(2)));

#define THREADS 512
#define BM      64
#define NBLK    512
#define NSTEP   6

// ws layout (bytes)
#define WIH_OFF 0u            // 96 nt * 16 kk * 64 lane * 16B = 1572864
#define WHH_OFF 1572864u
#define WOP_OFF 3145728u      // 16 kk * 64 lane * 16B = 16384
#define GI_OFF  4194304u      // 512 blk * 24576 chunks * 8B = 100663296

static __device__ __forceinline__ float sigm(float v) { return 1.0f / (1.0f + __expf(-v)); }
static __device__ __forceinline__ float tanhf_(float v) {
  v = fminf(fmaxf(v, -12.0f), 12.0f);
  float e = __expf(2.0f * v);
  return 1.0f - 2.0f / (e + 1.0f);
}
static __device__ __forceinline__ f32x4 up4(bf16x4 v) {
  f32x4 o; o[0] = (float)v[0]; o[1] = (float)v[1]; o[2] = (float)v[2]; o[3] = (float)v[3];
  return o;
}
static __device__ __forceinline__ bf16x4 pk4(f32x4 v) {
  bf16x4 o; o[0] = (bf16_t)v[0]; o[1] = (bf16_t)v[1]; o[2] = (bf16_t)v[2]; o[3] = (bf16_t)v[3];
  return o;
}

// Pack weights into MFMA A-frag order:
//   chunk[(nt*16 + kk)*64 + lane] = w[nt*16 + (lane&15)][kk*32 + (lane>>4)*8 .. +8]
__global__ void prep_kernel(const float* __restrict__ wih_f, const float* __restrict__ whh_f,
                            const float* __restrict__ wout_f,
                            bf16x8* __restrict__ wihPk, bf16x8* __restrict__ whhPk,
                            bf16x8* __restrict__ wopPk) {
  int c = blockIdx.x * 256 + threadIdx.x;
  int lane = c & 63, l15 = lane & 15, lk = (lane >> 4) & 3;
  if (c < 196608) {
    int cid = (c < 98304) ? c : c - 98304;
    const float* src = (c < 98304) ? wih_f : whh_f;
    bf16x8* dst = (c < 98304) ? wihPk : whhPk;
    int kk = (cid >> 6) & 15;
    int nt = cid >> 10;
    const float* p = src + (size_t)(nt * 16 + l15) * 512 + kk * 32 + lk * 8;
    bf16x8 o;
    #pragma unroll
    for (int i = 0; i < 8; ++i) o[i] = (bf16_t)p[i];
    dst[cid] = o;
  } else if (c < 197632) {
    int cid = c - 196608;          // vocab tile: 16 kk * 64 lane
    int kk = cid >> 6;
    bf16x8 o;
    if (l15 < 10) {
      const float* p = wout_f + (size_t)l15 * 512 + kk * 32 + lk * 8;
      #pragma unroll
      for (int i = 0; i < 8; ++i) o[i] = (bf16_t)p[i];
    } else {
      #pragma unroll
      for (int i = 0; i < 8; ++i) o[i] = (bf16_t)0.0f;
    }
    wopPk[cid] = o;
  }
}

__global__ __launch_bounds__(THREADS, 2) void gru_kernel(
    const float* __restrict__ x, const float* __restrict__ b_ih,
    const float* __restrict__ b_hh, const float* __restrict__ b_out,
    const bf16x8* __restrict__ wih, const bf16x8* __restrict__ whh,
    const bf16x8* __restrict__ wop,
    bf16x4* __restrict__ gi, float* __restrict__ out) {
  // h tile: 64 rows x 512 bf16, row = 1024B, logical byte L of row r stored at
  // physical L ^ ((r&7)<<4).
  __shared__ __align__(16) char hlds[BM * 1024];

  const int tid   = (int)threadIdx.x;
  const int lane  = tid & 63;
  const int wq    = tid >> 6;      // 0..7: wave owns jtiles [wq*4, wq*4+4)
  const int l15   = lane & 15;
  const int lk    = lane >> 4;
  const int brow0 = (int)blockIdx.x * BM;
  const int swz   = (l15 & 7) << 4;

  // ---------------- phase 0: x -> bf16 -> hlds (h0 = x) ----------------
  #pragma unroll
  for (int it = 0; it < 16; ++it) {
    int f4  = it * THREADS + tid;
    int row = f4 >> 7, c4 = f4 & 127;
    float4 v = ((const float4*)(x + (size_t)(brow0 + row) * 512))[c4];
    bf16x4 h4 = { (bf16_t)v.x, (bf16_t)v.y, (bf16_t)v.z, (bf16_t)v.w };
    *(bf16x4*)(&hlds[row * 1024 + ((c4 * 8) ^ ((row & 7) << 4))]) = h4;
  }
  __syncthreads();

  const size_t gibase = (size_t)blockIdx.x * 24576;  // bf16x4 chunks per block
  // gi chunk: ((jt*3 + g)*4 + bt)*64 + lane,  jt = wq*4 + p

  // ---------------- gi phase: gi = x @ w_ih^T + biases ----------------
  #pragma unroll
  for (int p = 0; p < 4; ++p) {
    const int jt = wq * 4 + p;
    f32x4 acc[3][4];
    #pragma unroll
    for (int g = 0; g < 3; ++g)
      #pragma unroll
      for (int bt = 0; bt < 4; ++bt) acc[g][bt] = (f32x4){0.f, 0.f, 0.f, 0.f};

    #pragma unroll 4
    for (int kk = 0; kk < 16; ++kk) {
      bf16x8 hf[4];
      #pragma unroll
      for (int bt = 0; bt < 4; ++bt)
        hf[bt] = *(const bf16x8*)(&hlds[(bt * 16 + l15) * 1024 +
                                        (((kk * 64) | (lk * 16)) ^ swz)]);
      #pragma unroll
      for (int g = 0; g < 3; ++g) {
        bf16x8 wf = wih[((g * 32 + jt) * 16 + kk) * 64 + lane];
        #pragma unroll
        for (int bt = 0; bt < 4; ++bt)
          acc[g][bt] = __builtin_amdgcn_mfma_f32_16x16x32_bf16(wf, hf[bt], acc[g][bt], 0, 0, 0);
      }
    }
    {
      int j = jt * 16 + lk * 4;
      f32x4 b0 = *(const f32x4*)(b_ih + j) + *(const f32x4*)(b_hh + j);
      f32x4 b1 = *(const f32x4*)(b_ih + 512 + j) + *(const f32x4*)(b_hh + 512 + j);
      f32x4 b2 = *(const f32x4*)(b_ih + 1024 + j);   // b_hh_n stays separate (x r)
      #pragma unroll
      for (int bt = 0; bt < 4; ++bt) {
        int cb = (jt * 3) * 4 + bt;
        gi[gibase + ((size_t)(cb + 0) << 6) + lane] = pk4(acc[0][bt] + b0);
        gi[gibase + ((size_t)(cb + 4) << 6) + lane] = pk4(acc[1][bt] + b1);
        gi[gibase + ((size_t)(cb + 8) << 6) + lane] = pk4(acc[2][bt] + b2);
      }
    }
  }
  // (no barrier: hlds unchanged; gi is same-lane RAW, HW-ordered)

  // ---------------- 6 recurrent steps ----------------
  for (int t = 0; t < NSTEP; ++t) {
    bf16x4 hnew[4][4];   // [p][bt], held across barrier #1 (statically indexed)
    #pragma unroll
    for (int p = 0; p < 4; ++p) {
      const int jt = wq * 4 + p;
      const int cb = (jt * 3) * 4;
      // prefetch r,z gi chunks (16 VGPR); gn loaded at epilogue start
      bf16x4 gpre[2][4];
      #pragma unroll
      for (int g = 0; g < 2; ++g)
        #pragma unroll
        for (int bt = 0; bt < 4; ++bt)
          gpre[g][bt] = gi[gibase + ((size_t)(cb + g * 4 + bt) << 6) + lane];

      f32x4 acc[3][4];
      #pragma unroll
      for (int g = 0; g < 3; ++g)
        #pragma unroll
        for (int bt = 0; bt < 4; ++bt) acc[g][bt] = (f32x4){0.f, 0.f, 0.f, 0.f};

      #pragma unroll 4
      for (int kk = 0; kk < 16; ++kk) {
        bf16x8 hf[4];
        #pragma unroll
        for (int bt = 0; bt < 4; ++bt)
          hf[bt] = *(const bf16x8*)(&hlds[(bt * 16 + l15) * 1024 +
                                          (((kk * 64) | (lk * 16)) ^ swz)]);
        #pragma unroll
        for (int g = 0; g < 3; ++g) {
          bf16x8 wf = whh[((g * 32 + jt) * 16 + kk) * 64 + lane];
          #pragma unroll
          for (int bt = 0; bt < 4; ++bt)
            acc[g][bt] = __builtin_amdgcn_mfma_f32_16x16x32_bf16(wf, hf[bt], acc[g][bt], 0, 0, 0);
        }
      }
      // GRU cell epilogue
      {
        int j = jt * 16 + lk * 4;
        f32x4 bn4 = *(const f32x4*)(b_hh + 1024 + j);
        bf16x4 gnp[4];
        #pragma unroll
        for (int bt = 0; bt < 4; ++bt)
          gnp[bt] = gi[gibase + ((size_t)(cb + 8 + bt) << 6) + lane];
        #pragma unroll
        for (int bt = 0; bt < 4; ++bt) {
          f32x4 gr = up4(gpre[0][bt]);
          f32x4 gz = up4(gpre[1][bt]);
          bf16x4 ho = *(const bf16x4*)(&hlds[(bt * 16 + l15) * 1024 +
                                             (((jt * 32) | (lk * 8)) ^ swz)]);
          f32x4 hov = up4(ho);
          f32x4 gn = up4(gnp[bt]);
          f32x4 hv;
          #pragma unroll
          for (int r = 0; r < 4; ++r) {
            float rv = sigm(gr[r] + acc[0][bt][r]);
            float zv = sigm(gz[r] + acc[1][bt][r]);
            float nv = tanhf_(gn[r] + rv * (acc[2][bt][r] + bn4[r]));
            hv[r] = (1.0f - zv) * nv + zv * hov[r];
          }
          hnew[p][bt] = pk4(hv);
        }
      }
    }
    __syncthreads();   // all waves done reading h_t
    #pragma unroll
    for (int p = 0; p < 4; ++p)
      #pragma unroll
      for (int bt = 0; bt < 4; ++bt)
        *(bf16x4*)(&hlds[(bt * 16 + l15) * 1024 +
                         ((((wq * 4 + p) * 32) | (lk * 8)) ^ swz)]) = hnew[p][bt];
    __syncthreads();   // h_{t+1} visible

    // logits_t = h_{t+1} @ w_out^T + b_out ; waves 0..3 each own one btile
    if (wq < 4) {
      f32x4 lacc = (f32x4){0.f, 0.f, 0.f, 0.f};
      #pragma unroll 4
      for (int kk = 0; kk < 16; ++kk) {
        bf16x8 hf = *(const bf16x8*)(&hlds[(wq * 16 + l15) * 1024 +
                                           (((kk * 64) | (lk * 16)) ^ swz)]);
        bf16x8 wf = wop[kk * 64 + lane];
        lacc = __builtin_amdgcn_mfma_f32_16x16x32_bf16(wf, hf, lacc, 0, 0, 0);
      }
      size_t ob = (size_t)(brow0 + wq * 16 + l15) * 60 + t * 10 + lk * 4;
      if (lk < 2) {
        f32x2 a = { lacc[0] + b_out[lk * 4 + 0], lacc[1] + b_out[lk * 4 + 1] };
        f32x2 b = { lacc[2] + b_out[lk * 4 + 2], lacc[3] + b_out[lk * 4 + 3] };
        *(f32x2*)(out + ob) = a;
        *(f32x2*)(out + ob + 2) = b;
      } else if (lk == 2) {
        f32x2 a = { lacc[0] + b_out[8], lacc[1] + b_out[9] };
        *(f32x2*)(out + ob) = a;
      }
    }
  }
}

extern "C" void kernel_launch(void* const* d_in, const int* in_sizes, int n_in,
                              void* d_out, int out_size, void* d_ws, size_t ws_size,
                              hipStream_t stream) {
  const float* x     = (const float*)d_in[0];
  const float* wih_f = (const float*)d_in[1];
  const float* whh_f = (const float*)d_in[2];
  const float* b_ih  = (const float*)d_in[3];
  const float* b_hh  = (const float*)d_in[4];
  const float* wout  = (const float*)d_in[5];
  const float* b_out = (const float*)d_in[6];

  char* ws = (char*)d_ws;
  bf16x8* wihPk = (bf16x8*)(ws + WIH_OFF);
  bf16x8* whhPk = (bf16x8*)(ws + WHH_OFF);
  bf16x8* wopPk = (bf16x8*)(ws + WOP_OFF);
  bf16x4* gi    = (bf16x4*)(ws + GI_OFF);

  prep_kernel<<<772, 256, 0, stream>>>(wih_f, whh_f, wout, wihPk, whhPk, wopPk);
  gru_kernel<<<NBLK, THREADS, 0, stream>>>(x, b_ih, b_hh, b_out,
                                           wihPk, whhPk, wopPk, gi, (float*)d_out);
}

// Round 5
// 994.997 us; speedup vs baseline: 2.2479x; 1.1920x over previous
//
#include <hip/hip_runtime.h>
#include <hip/hip_bf16.h>
#include <stdint.h>

// GRU sequence decoder, fused. B=32768, H=L=512, VOCAB=10, SEQ=6.
// R5: de-spill R4. Evidence R4: WRITE_SIZE 1.03GB (~0.9GB scratch stores),
// VGPR=128 (at cap), occupancy stuck at 22%. Fix: remove gpre prefetch
// (-16 regs live across k-loop), kk unroll 4->2 (-~16 in-flight), hoisted
// swizzle base. Structure unchanged from R4:
//  - 8 waves, wave owns 4 jtiles x all 4 btiles (weight-chunk read once per
//    block-step: L2 weight traffic 5.4 GB total).
//  - A = weight frag (M = j), B = h frag (N = batch); lane holds D[j-contig].
//  - gi in ws in per-lane fragment order (bf16x4/lane), coalesced; loaded in
//    the cell epilogue (same-lane RAW, no cross-wave sync needed).
//  - h lives only in LDS (XOR-swizzle: col bytes ^= (l15&7)<<4, bijective per
//    1024B row); h_new carried in regs across barrier then ds_write_b64.
//  - __launch_bounds__(512,2): hipcc 2nd arg = min BLOCKS/CU (measured R3).

typedef __bf16 bf16_t;
typedef bf16_t bf16x8 __attribute__((ext_vector_type(8)));
typedef bf16_t bf16x4 __attribute__((ext_vector_type(4)));
typedef float  f32x4  __attribute__((ext_vector_type(4)));
typedef float  f32x2  __attribute__((ext_vector_type(2)));

#define THREADS 512
#define BM      64
#define NBLK    512
#define NSTEP   6

// ws layout (bytes)
#define WIH_OFF 0u            // 96 nt * 16 kk * 64 lane * 16B = 1572864
#define WHH_OFF 1572864u
#define WOP_OFF 3145728u      // 16 kk * 64 lane * 16B = 16384
#define GI_OFF  4194304u      // 512 blk * 24576 chunks * 8B = 100663296

static __device__ __forceinline__ float sigm(float v) { return 1.0f / (1.0f + __expf(-v)); }
static __device__ __forceinline__ float tanhf_(float v) {
  v = fminf(fmaxf(v, -12.0f), 12.0f);
  float e = __expf(2.0f * v);
  return 1.0f - 2.0f / (e + 1.0f);
}
static __device__ __forceinline__ f32x4 up4(bf16x4 v) {
  f32x4 o; o[0] = (float)v[0]; o[1] = (float)v[1]; o[2] = (float)v[2]; o[3] = (float)v[3];
  return o;
}
static __device__ __forceinline__ bf16x4 pk4(f32x4 v) {
  bf16x4 o; o[0] = (bf16_t)v[0]; o[1] = (bf16_t)v[1]; o[2] = (bf16_t)v[2]; o[3] = (bf16_t)v[3];
  return o;
}

// Pack weights into MFMA A-frag order:
//   chunk[(nt*16 + kk)*64 + lane] = w[nt*16 + (lane&15)][kk*32 + (lane>>4)*8 .. +8]
__global__ void prep_kernel(const float* __restrict__ wih_f, const float* __restrict__ whh_f,
                            const float* __restrict__ wout_f,
                            bf16x8* __restrict__ wihPk, bf16x8* __restrict__ whhPk,
                            bf16x8* __restrict__ wopPk) {
  int c = blockIdx.x * 256 + threadIdx.x;
  int lane = c & 63, l15 = lane & 15, lk = (lane >> 4) & 3;
  if (c < 196608) {
    int cid = (c < 98304) ? c : c - 98304;
    const float* src = (c < 98304) ? wih_f : whh_f;
    bf16x8* dst = (c < 98304) ? wihPk : whhPk;
    int kk = (cid >> 6) & 15;
    int nt = cid >> 10;
    const float* p = src + (size_t)(nt * 16 + l15) * 512 + kk * 32 + lk * 8;
    bf16x8 o;
    #pragma unroll
    for (int i = 0; i < 8; ++i) o[i] = (bf16_t)p[i];
    dst[cid] = o;
  } else if (c < 197632) {
    int cid = c - 196608;          // vocab tile: 16 kk * 64 lane
    int kk = cid >> 6;
    bf16x8 o;
    if (l15 < 10) {
      const float* p = wout_f + (size_t)l15 * 512 + kk * 32 + lk * 8;
      #pragma unroll
      for (int i = 0; i < 8; ++i) o[i] = (bf16_t)p[i];
    } else {
      #pragma unroll
      for (int i = 0; i < 8; ++i) o[i] = (bf16_t)0.0f;
    }
    wopPk[cid] = o;
  }
}

__global__ __launch_bounds__(THREADS, 2) void gru_kernel(
    const float* __restrict__ x, const float* __restrict__ b_ih,
    const float* __restrict__ b_hh, const float* __restrict__ b_out,
    const bf16x8* __restrict__ wih, const bf16x8* __restrict__ whh,
    const bf16x8* __restrict__ wop,
    bf16x4* __restrict__ gi, float* __restrict__ out) {
  // h tile: 64 rows x 512 bf16, row = 1024B; logical col-byte L of row r at
  // physical L ^ ((r&7)<<4).
  __shared__ __align__(16) char hlds[BM * 1024];

  const int tid   = (int)threadIdx.x;
  const int lane  = tid & 63;
  const int wq    = tid >> 6;      // 0..7: wave owns jtiles [wq*4, wq*4+4)
  const int l15   = lane & 15;
  const int lk    = lane >> 4;
  const int brow0 = (int)blockIdx.x * BM;
  const int swz   = (l15 & 7) << 4;
  const int kbase = (lk * 16) ^ swz;        // b128 read col base (XOR with kk*64)
  const int cbase = (lk * 8) ^ swz;         // b64 cell col base (XOR with jt*32)

  // ---------------- phase 0: x -> bf16 -> hlds (h0 = x) ----------------
  #pragma unroll
  for (int it = 0; it < 16; ++it) {
    int f4  = it * THREADS + tid;
    int row = f4 >> 7, c4 = f4 & 127;
    float4 v = ((const float4*)(x + (size_t)(brow0 + row) * 512))[c4];
    bf16x4 h4 = { (bf16_t)v.x, (bf16_t)v.y, (bf16_t)v.z, (bf16_t)v.w };
    *(bf16x4*)(&hlds[row * 1024 + ((c4 * 8) ^ ((row & 7) << 4))]) = h4;
  }
  __syncthreads();

  const size_t gibase = (size_t)blockIdx.x * 24576;  // bf16x4 chunks per block
  // gi chunk: ((jt*3 + g)*4 + bt)*64 + lane,  jt = wq*4 + p

  // ---------------- gi phase: gi = x @ w_ih^T + biases ----------------
  #pragma unroll
  for (int p = 0; p < 4; ++p) {
    const int jt = wq * 4 + p;
    f32x4 acc[3][4];
    #pragma unroll
    for (int g = 0; g < 3; ++g)
      #pragma unroll
      for (int bt = 0; bt < 4; ++bt) acc[g][bt] = (f32x4){0.f, 0.f, 0.f, 0.f};

    #pragma unroll 2
    for (int kk = 0; kk < 16; ++kk) {
      bf16x8 hf[4];
      #pragma unroll
      for (int bt = 0; bt < 4; ++bt)
        hf[bt] = *(const bf16x8*)(&hlds[(bt * 16 + l15) * 1024 + ((kk * 64) ^ kbase)]);
      #pragma unroll
      for (int g = 0; g < 3; ++g) {
        bf16x8 wf = wih[((g * 32 + jt) * 16 + kk) * 64 + lane];
        #pragma unroll
        for (int bt = 0; bt < 4; ++bt)
          acc[g][bt] = __builtin_amdgcn_mfma_f32_16x16x32_bf16(wf, hf[bt], acc[g][bt], 0, 0, 0);
      }
    }
    {
      int j = jt * 16 + lk * 4;
      f32x4 b0 = *(const f32x4*)(b_ih + j) + *(const f32x4*)(b_hh + j);
      f32x4 b1 = *(const f32x4*)(b_ih + 512 + j) + *(const f32x4*)(b_hh + 512 + j);
      f32x4 b2 = *(const f32x4*)(b_ih + 1024 + j);   // b_hh_n stays separate (x r)
      #pragma unroll
      for (int bt = 0; bt < 4; ++bt) {
        int cb = (jt * 3) * 4 + bt;
        gi[gibase + ((size_t)(cb + 0) << 6) + lane] = pk4(acc[0][bt] + b0);
        gi[gibase + ((size_t)(cb + 4) << 6) + lane] = pk4(acc[1][bt] + b1);
        gi[gibase + ((size_t)(cb + 8) << 6) + lane] = pk4(acc[2][bt] + b2);
      }
    }
  }
  // (no barrier: hlds unchanged; gi is same-lane RAW, HW-ordered)

  // ---------------- 6 recurrent steps ----------------
  for (int t = 0; t < NSTEP; ++t) {
    bf16x4 hnew[4][4];   // [p][bt], held across barrier #1 (statically indexed)
    #pragma unroll
    for (int p = 0; p < 4; ++p) {
      const int jt = wq * 4 + p;
      const int cb = (jt * 3) * 4;

      f32x4 acc[3][4];
      #pragma unroll
      for (int g = 0; g < 3; ++g)
        #pragma unroll
        for (int bt = 0; bt < 4; ++bt) acc[g][bt] = (f32x4){0.f, 0.f, 0.f, 0.f};

      #pragma unroll 2
      for (int kk = 0; kk < 16; ++kk) {
        bf16x8 hf[4];
        #pragma unroll
        for (int bt = 0; bt < 4; ++bt)
          hf[bt] = *(const bf16x8*)(&hlds[(bt * 16 + l15) * 1024 + ((kk * 64) ^ kbase)]);
        #pragma unroll
        for (int g = 0; g < 3; ++g) {
          bf16x8 wf = whh[((g * 32 + jt) * 16 + kk) * 64 + lane];
          #pragma unroll
          for (int bt = 0; bt < 4; ++bt)
            acc[g][bt] = __builtin_amdgcn_mfma_f32_16x16x32_bf16(wf, hf[bt], acc[g][bt], 0, 0, 0);
        }
      }
      // GRU cell epilogue (gi loaded here, while acc is dying)
      {
        int j = jt * 16 + lk * 4;
        f32x4 bn4 = *(const f32x4*)(b_hh + 1024 + j);
        #pragma unroll
        for (int bt = 0; bt < 4; ++bt) {
          bf16x4 grp = gi[gibase + ((size_t)(cb + 0 + bt) << 6) + lane];
          bf16x4 gzp = gi[gibase + ((size_t)(cb + 4 + bt) << 6) + lane];
          bf16x4 gnp = gi[gibase + ((size_t)(cb + 8 + bt) << 6) + lane];
          bf16x4 ho  = *(const bf16x4*)(&hlds[(bt * 16 + l15) * 1024 +
                                              ((jt * 32) ^ cbase)]);
          f32x4 gr = up4(grp), gz = up4(gzp), gn = up4(gnp), hov = up4(ho);
          f32x4 hv;
          #pragma unroll
          for (int r = 0; r < 4; ++r) {
            float rv = sigm(gr[r] + acc[0][bt][r]);
            float zv = sigm(gz[r] + acc[1][bt][r]);
            float nv = tanhf_(gn[r] + rv * (acc[2][bt][r] + bn4[r]));
            hv[r] = (1.0f - zv) * nv + zv * hov[r];
          }
          hnew[p][bt] = pk4(hv);
        }
      }
    }
    __syncthreads();   // all waves done reading h_t
    #pragma unroll
    for (int p = 0; p < 4; ++p)
      #pragma unroll
      for (int bt = 0; bt < 4; ++bt)
        *(bf16x4*)(&hlds[(bt * 16 + l15) * 1024 +
                         (((wq * 4 + p) * 32) ^ cbase)]) = hnew[p][bt];
    __syncthreads();   // h_{t+1} visible

    // logits_t = h_{t+1} @ w_out^T + b_out ; waves 0..3 each own one btile
    if (wq < 4) {
      f32x4 lacc = (f32x4){0.f, 0.f, 0.f, 0.f};
      #pragma unroll 2
      for (int kk = 0; kk < 16; ++kk) {
        bf16x8 hf = *(const bf16x8*)(&hlds[(wq * 16 + l15) * 1024 + ((kk * 64) ^ kbase)]);
        bf16x8 wf = wop[kk * 64 + lane];
        lacc = __builtin_amdgcn_mfma_f32_16x16x32_bf16(wf, hf, lacc, 0, 0, 0);
      }
      size_t ob = (size_t)(brow0 + wq * 16 + l15) * 60 + t * 10 + lk * 4;
      if (lk < 2) {
        f32x2 a = { lacc[0] + b_out[lk * 4 + 0], lacc[1] + b_out[lk * 4 + 1] };
        f32x2 b = { lacc[2] + b_out[lk * 4 + 2], lacc[3] + b_out[lk * 4 + 3] };
        *(f32x2*)(out + ob) = a;
        *(f32x2*)(out + ob + 2) = b;
      } else if (lk == 2) {
        f32x2 a = { lacc[0] + b_out[8], lacc[1] + b_out[9] };
        *(f32x2*)(out + ob) = a;
      }
    }
  }
}

extern "C" void kernel_launch(void* const* d_in, const int* in_sizes, int n_in,
                              void* d_out, int out_size, void* d_ws, size_t ws_size,
                              hipStream_t stream) {
  const float* x     = (const float*)d_in[0];
  const float* wih_f = (const float*)d_in[1];
  const float* whh_f = (const float*)d_in[2];
  const float* b_ih  = (const float*)d_in[3];
  const float* b_hh  = (const float*)d_in[4];
  const float* wout  = (const float*)d_in[5];
  const float* b_out = (const float*)d_in[6];

  char* ws = (char*)d_ws;
  bf16x8* wihPk = (bf16x8*)(ws + WIH_OFF);
  bf16x8* whhPk = (bf16x8*)(ws + WHH_OFF);
  bf16x8* wopPk = (bf16x8*)(ws + WOP_OFF);
  bf16x4* gi    = (bf16x4*)(ws + GI_OFF);

  prep_kernel<<<772, 256, 0, stream>>>(wih_f, whh_f, wout, wihPk, whhPk, wopPk);
  gru_kernel<<<NBLK, THREADS, 0, stream>>>(x, b_ih, b_hh, b_out,
                                           wihPk, whhPk, wopPk, gi, (float*)d_out);
}

// Round 6
// 600.358 us; speedup vs baseline: 3.7255x; 1.6573x over previous
//
#include <hip/hip_runtime.h>
#include <hip/hip_bf16.h>
#include <stdint.h>

// GRU sequence decoder, fused. B=32768, H=L=512, VOCAB=10, SEQ=6.
// R6: de-spill for real. R5 evidence: WRITE_SIZE 832MB (~700MB scratch),
// VGPR=128 pinned, occupancy stuck ~23% (scratch slots cap resident waves).
// Crunch = hnew[4][4] (32 VGPR) held across the whole p-loop + barrier.
// Fix: stream h_new through coalesced GLOBAL staging (hst, 32MB, L2-resident):
// epilogue stores each bf16x4 chunk immediately (frees regs); after barrier
// the SAME thread reloads its own chunks and ds_writes hlds (R2-validated
// round-trip; __syncthreads orders block-level global RAW, vmcnt drained).
// Everything else identical to R5:
//  - 8 waves, wave owns 4 jtiles x all 4 btiles (weight chunk read once per
//    block-step; L2 weight traffic ~5.5GB total).
//  - A = weight frag (M = j), B = h frag (N = batch); lane holds D[j-contig].
//  - gi in ws per-lane fragment order, loaded in cell epilogue (same-lane RAW).
//  - h only in LDS (XOR swizzle), single buffer 64KB -> 2 blocks/CU target.
//  - __launch_bounds__(512,2): hipcc 2nd arg = min BLOCKS/CU (measured R3).

typedef __bf16 bf16_t;
typedef bf16_t bf16x8 __attribute__((ext_vector_type(8)));
typedef bf16_t bf16x4 __attribute__((ext_vector_type(4)));
typedef float  f32x4  __attribute__((ext_vector_type(4)));
typedef float  f32x2  __attribute__((ext_vector_type(2)));

#define THREADS 512
#define BM      64
#define NBLK    512
#define NSTEP   6

// ws layout (bytes)
#define WIH_OFF 0u            // 96 nt * 16 kk * 64 lane * 16B = 1572864
#define WHH_OFF 1572864u
#define WOP_OFF 3145728u      // 16 kk * 64 lane * 16B = 16384
#define GI_OFF  4194304u      // 512 blk * 24576 chunks * 8B = 100663296
#define HST_OFF 104857600u    // 512 blk * 128 chunks * 512B = 33554432 (end 138412032)

static __device__ __forceinline__ float sigm(float v) { return 1.0f / (1.0f + __expf(-v)); }
static __device__ __forceinline__ float tanhf_(float v) {
  v = fminf(fmaxf(v, -12.0f), 12.0f);
  float e = __expf(2.0f * v);
  return 1.0f - 2.0f / (e + 1.0f);
}
static __device__ __forceinline__ f32x4 up4(bf16x4 v) {
  f32x4 o; o[0] = (float)v[0]; o[1] = (float)v[1]; o[2] = (float)v[2]; o[3] = (float)v[3];
  return o;
}
static __device__ __forceinline__ bf16x4 pk4(f32x4 v) {
  bf16x4 o; o[0] = (bf16_t)v[0]; o[1] = (bf16_t)v[1]; o[2] = (bf16_t)v[2]; o[3] = (bf16_t)v[3];
  return o;
}

// Pack weights into MFMA A-frag order:
//   chunk[(nt*16 + kk)*64 + lane] = w[nt*16 + (lane&15)][kk*32 + (lane>>4)*8 .. +8]
__global__ void prep_kernel(const float* __restrict__ wih_f, const float* __restrict__ whh_f,
                            const float* __restrict__ wout_f,
                            bf16x8* __restrict__ wihPk, bf16x8* __restrict__ whhPk,
                            bf16x8* __restrict__ wopPk) {
  int c = blockIdx.x * 256 + threadIdx.x;
  int lane = c & 63, l15 = lane & 15, lk = (lane >> 4) & 3;
  if (c < 196608) {
    int cid = (c < 98304) ? c : c - 98304;
    const float* src = (c < 98304) ? wih_f : whh_f;
    bf16x8* dst = (c < 98304) ? wihPk : whhPk;
    int kk = (cid >> 6) & 15;
    int nt = cid >> 10;
    const float* p = src + (size_t)(nt * 16 + l15) * 512 + kk * 32 + lk * 8;
    bf16x8 o;
    #pragma unroll
    for (int i = 0; i < 8; ++i) o[i] = (bf16_t)p[i];
    dst[cid] = o;
  } else if (c < 197632) {
    int cid = c - 196608;          // vocab tile: 16 kk * 64 lane
    int kk = cid >> 6;
    bf16x8 o;
    if (l15 < 10) {
      const float* p = wout_f + (size_t)l15 * 512 + kk * 32 + lk * 8;
      #pragma unroll
      for (int i = 0; i < 8; ++i) o[i] = (bf16_t)p[i];
    } else {
      #pragma unroll
      for (int i = 0; i < 8; ++i) o[i] = (bf16_t)0.0f;
    }
    wopPk[cid] = o;
  }
}

__global__ __launch_bounds__(THREADS, 2) void gru_kernel(
    const float* __restrict__ x, const float* __restrict__ b_ih,
    const float* __restrict__ b_hh, const float* __restrict__ b_out,
    const bf16x8* __restrict__ wih, const bf16x8* __restrict__ whh,
    const bf16x8* __restrict__ wop,
    bf16x4* __restrict__ gi, bf16x4* __restrict__ hst, float* __restrict__ out) {
  // h tile: 64 rows x 512 bf16, row = 1024B; logical col-byte L of row r at
  // physical L ^ ((r&7)<<4).
  __shared__ __align__(16) char hlds[BM * 1024];

  const int tid   = (int)threadIdx.x;
  const int lane  = tid & 63;
  const int wq    = tid >> 6;      // 0..7: wave owns jtiles [wq*4, wq*4+4)
  const int l15   = lane & 15;
  const int lk    = lane >> 4;
  const int brow0 = (int)blockIdx.x * BM;
  const int swz   = (l15 & 7) << 4;
  const int kbase = (lk * 16) ^ swz;        // b128 read col base (XOR with kk*64)
  const int cbase = (lk * 8) ^ swz;         // b64 cell col base (XOR with jt*32)

  // ---------------- phase 0: x -> bf16 -> hlds (h0 = x) ----------------
  #pragma unroll
  for (int it = 0; it < 16; ++it) {
    int f4  = it * THREADS + tid;
    int row = f4 >> 7, c4 = f4 & 127;
    float4 v = ((const float4*)(x + (size_t)(brow0 + row) * 512))[c4];
    bf16x4 h4 = { (bf16_t)v.x, (bf16_t)v.y, (bf16_t)v.z, (bf16_t)v.w };
    *(bf16x4*)(&hlds[row * 1024 + ((c4 * 8) ^ ((row & 7) << 4))]) = h4;
  }
  __syncthreads();

  const size_t gibase = (size_t)blockIdx.x * 24576;  // bf16x4 chunks per block
  // gi chunk: ((jt*3 + g)*4 + bt)*64 + lane,  jt = wq*4 + p
  const size_t hstbase = (size_t)blockIdx.x * 8192;  // bf16x4: 128 chunks * 64
  // hst chunk: (jt*4 + bt)*64 + lane

  // ---------------- gi phase: gi = x @ w_ih^T + biases ----------------
  #pragma unroll
  for (int p = 0; p < 4; ++p) {
    const int jt = wq * 4 + p;
    f32x4 acc[3][4];
    #pragma unroll
    for (int g = 0; g < 3; ++g)
      #pragma unroll
      for (int bt = 0; bt < 4; ++bt) acc[g][bt] = (f32x4){0.f, 0.f, 0.f, 0.f};

    #pragma unroll 2
    for (int kk = 0; kk < 16; ++kk) {
      bf16x8 hf[4];
      #pragma unroll
      for (int bt = 0; bt < 4; ++bt)
        hf[bt] = *(const bf16x8*)(&hlds[(bt * 16 + l15) * 1024 + ((kk * 64) ^ kbase)]);
      #pragma unroll
      for (int g = 0; g < 3; ++g) {
        bf16x8 wf = wih[((g * 32 + jt) * 16 + kk) * 64 + lane];
        #pragma unroll
        for (int bt = 0; bt < 4; ++bt)
          acc[g][bt] = __builtin_amdgcn_mfma_f32_16x16x32_bf16(wf, hf[bt], acc[g][bt], 0, 0, 0);
      }
    }
    {
      int j = jt * 16 + lk * 4;
      f32x4 b0 = *(const f32x4*)(b_ih + j) + *(const f32x4*)(b_hh + j);
      f32x4 b1 = *(const f32x4*)(b_ih + 512 + j) + *(const f32x4*)(b_hh + 512 + j);
      f32x4 b2 = *(const f32x4*)(b_ih + 1024 + j);   // b_hh_n stays separate (x r)
      #pragma unroll
      for (int bt = 0; bt < 4; ++bt) {
        int cb = (jt * 3) * 4 + bt;
        gi[gibase + ((size_t)(cb + 0) << 6) + lane] = pk4(acc[0][bt] + b0);
        gi[gibase + ((size_t)(cb + 4) << 6) + lane] = pk4(acc[1][bt] + b1);
        gi[gibase + ((size_t)(cb + 8) << 6) + lane] = pk4(acc[2][bt] + b2);
      }
    }
  }
  // (no barrier: hlds unchanged; gi is same-lane RAW, HW-ordered)

  // ---------------- 6 recurrent steps ----------------
  for (int t = 0; t < NSTEP; ++t) {
    #pragma unroll
    for (int p = 0; p < 4; ++p) {
      const int jt = wq * 4 + p;
      const int cb = (jt * 3) * 4;

      f32x4 acc[3][4];
      #pragma unroll
      for (int g = 0; g < 3; ++g)
        #pragma unroll
        for (int bt = 0; bt < 4; ++bt) acc[g][bt] = (f32x4){0.f, 0.f, 0.f, 0.f};

      #pragma unroll 2
      for (int kk = 0; kk < 16; ++kk) {
        bf16x8 hf[4];
        #pragma unroll
        for (int bt = 0; bt < 4; ++bt)
          hf[bt] = *(const bf16x8*)(&hlds[(bt * 16 + l15) * 1024 + ((kk * 64) ^ kbase)]);
        #pragma unroll
        for (int g = 0; g < 3; ++g) {
          bf16x8 wf = whh[((g * 32 + jt) * 16 + kk) * 64 + lane];
          #pragma unroll
          for (int bt = 0; bt < 4; ++bt)
            acc[g][bt] = __builtin_amdgcn_mfma_f32_16x16x32_bf16(wf, hf[bt], acc[g][bt], 0, 0, 0);
        }
      }
      // GRU cell epilogue: gi loaded here; h_new streamed straight to hst
      // (coalesced 512B/wave stores; registers freed immediately -> no hold).
      {
        int j = jt * 16 + lk * 4;
        f32x4 bn4 = *(const f32x4*)(b_hh + 1024 + j);
        #pragma unroll
        for (int bt = 0; bt < 4; ++bt) {
          bf16x4 grp = gi[gibase + ((size_t)(cb + 0 + bt) << 6) + lane];
          bf16x4 gzp = gi[gibase + ((size_t)(cb + 4 + bt) << 6) + lane];
          bf16x4 gnp = gi[gibase + ((size_t)(cb + 8 + bt) << 6) + lane];
          bf16x4 ho  = *(const bf16x4*)(&hlds[(bt * 16 + l15) * 1024 +
                                              ((jt * 32) ^ cbase)]);
          f32x4 gr = up4(grp), gz = up4(gzp), gn = up4(gnp), hov = up4(ho);
          f32x4 hv;
          #pragma unroll
          for (int r = 0; r < 4; ++r) {
            float rv = sigm(gr[r] + acc[0][bt][r]);
            float zv = sigm(gz[r] + acc[1][bt][r]);
            float nv = tanhf_(gn[r] + rv * (acc[2][bt][r] + bn4[r]));
            hv[r] = (1.0f - zv) * nv + zv * hov[r];
          }
          hst[hstbase + ((size_t)((jt << 2) + bt) << 6) + lane] = pk4(hv);
        }
      }
    }
    __syncthreads();   // all waves done reading h_t; hst stores drained (vmcnt)

    // copy-back: reload own chunks from hst (L2-hit, coalesced), ds_write hlds
    #pragma unroll
    for (int p = 0; p < 4; ++p) {
      const int jt = wq * 4 + p;
      #pragma unroll
      for (int bt = 0; bt < 4; ++bt) {
        bf16x4 v = hst[hstbase + ((size_t)((jt << 2) + bt) << 6) + lane];
        *(bf16x4*)(&hlds[(bt * 16 + l15) * 1024 + ((jt * 32) ^ cbase)]) = v;
      }
    }
    __syncthreads();   // h_{t+1} visible

    // logits_t = h_{t+1} @ w_out^T + b_out ; waves 0..3 each own one btile
    if (wq < 4) {
      f32x4 lacc = (f32x4){0.f, 0.f, 0.f, 0.f};
      #pragma unroll 2
      for (int kk = 0; kk < 16; ++kk) {
        bf16x8 hf = *(const bf16x8*)(&hlds[(wq * 16 + l15) * 1024 + ((kk * 64) ^ kbase)]);
        bf16x8 wf = wop[kk * 64 + lane];
        lacc = __builtin_amdgcn_mfma_f32_16x16x32_bf16(wf, hf, lacc, 0, 0, 0);
      }
      size_t ob = (size_t)(brow0 + wq * 16 + l15) * 60 + t * 10 + lk * 4;
      if (lk < 2) {
        f32x2 a = { lacc[0] + b_out[lk * 4 + 0], lacc[1] + b_out[lk * 4 + 1] };
        f32x2 b = { lacc[2] + b_out[lk * 4 + 2], lacc[3] + b_out[lk * 4 + 3] };
        *(f32x2*)(out + ob) = a;
        *(f32x2*)(out + ob + 2) = b;
      } else if (lk == 2) {
        f32x2 a = { lacc[0] + b_out[8], lacc[1] + b_out[9] };
        *(f32x2*)(out + ob) = a;
      }
    }
  }
}

extern "C" void kernel_launch(void* const* d_in, const int* in_sizes, int n_in,
                              void* d_out, int out_size, void* d_ws, size_t ws_size,
                              hipStream_t stream) {
  const float* x     = (const float*)d_in[0];
  const float* wih_f = (const float*)d_in[1];
  const float* whh_f = (const float*)d_in[2];
  const float* b_ih  = (const float*)d_in[3];
  const float* b_hh  = (const float*)d_in[4];
  const float* wout  = (const float*)d_in[5];
  const float* b_out = (const float*)d_in[6];

  char* ws = (char*)d_ws;
  bf16x8* wihPk = (bf16x8*)(ws + WIH_OFF);
  bf16x8* whhPk = (bf16x8*)(ws + WHH_OFF);
  bf16x8* wopPk = (bf16x8*)(ws + WOP_OFF);
  bf16x4* gi    = (bf16x4*)(ws + GI_OFF);
  bf16x4* hst   = (bf16x4*)(ws + HST_OFF);

  prep_kernel<<<772, 256, 0, stream>>>(wih_f, whh_f, wout, wihPk, whhPk, wopPk);
  gru_kernel<<<NBLK, THREADS, 0, stream>>>(x, b_ih, b_hh, b_out,
                                           wihPk, whhPk, wopPk, gi, hst, (float*)d_out);
}